// Round 4
// baseline (691.493 us; speedup 1.0000x reference)
//
#include <hip/hip_runtime.h>

// Bottleneck_refine: B=16, C=1024, H=W=56, G=4, MS=7 (8x8 patches), MID=256.
// One workgroup (256 thr = 4 waves) per (b,pr,pc,g): 3136 blocks.
//
// V4b = V3 + XCD-aware swizzle + nontemporal out stores (compile-fixed:
// nontemporal builtin needs native vector types, use ext_vector f4).
//  - Swizzle: all 49 patches of one (b,g) slab -> SAME XCD (bid%8 heuristic),
//    pc fastest. The 7 pc-neighbors consuming each 128B x-line now share one
//    XCD's L2 -> line fetched from HBM once (V3 fetched it per-XCD, ~200MB
//    over-fetch). Residual re-read also hits the local L2.
//  - out is never re-read -> nontemporal stores, don't evict x slab from L2.
//  - LDS 51968 B -> 3 blocks/CU. Weights LDS-staged from bf16 prepped image.
//
// LDS overlay (shorts):
//   phase1: XT[64][266] @0 (17024) + W1s[64][140] @17024 (8960)  = 25984
//   phase2: Y1[100][72] @0 (7200) + W2dbuf 2x[64][72] @7200 (9216)
//           + Y2[64][72] @21376 (4608)
//   phase3: W3s[256][72] @0 (18432) + Y2 @21376
//
// d_ws (shorts): W1I[g][64][256] @0, W2I[g][9][64][64] @65536,
//                W3I[g][256][64] @212992.  total 557056 B.

typedef __attribute__((ext_vector_type(8))) short bfrag;      // 8 bf16
typedef __attribute__((ext_vector_type(4))) float f4;

__device__ __forceinline__ unsigned short f2bf(float f) {
    union { float f; unsigned int i; } v; v.f = f;
    unsigned int u = v.i;
    return (unsigned short)((u + 0x7FFFu + ((u >> 16) & 1u)) >> 16);
}

__global__ __launch_bounds__(256)
void prep_weights(const float* __restrict__ w1, const float* __restrict__ w2,
                  const float* __restrict__ w3, unsigned short* __restrict__ wb) {
    int i = blockIdx.x * 256 + threadIdx.x;   // 1088 blocks * 256 = 278528
    if (i < 65536) {
        wb[i] = f2bf(w1[i]);                  // [g*64+oc][ic]
    } else if (i < 212992) {
        int j = i - 65536;
        int ic = j & 63, ocl = (j >> 6) & 63, gt = j >> 12;  // gt = g*9+tap
        int tap = gt % 9, g = gt / 9;
        wb[i] = f2bf(w2[(size_t)((g * 64 + ocl) * 64 + ic) * 9 + tap]);
    } else {
        wb[i] = f2bf(w3[i - 212992]);         // [g*256+oc][ic]
    }
}

#define XT_S 266   // XT stride: 133 dw/row, odd -> conflict-light reads
#define W1_S 140   // 70 dw/row
#define S72  72    // Y1 / W2 / Y2 / W3 stride (36 dw/row)
#define W1_OFF 17024
#define W2_OFF 7200
#define Y2_OFF 21376

__global__ __launch_bounds__(256, 3)
void bottleneck_kernel(const float* __restrict__ x,
                       const float* __restrict__ mask,
                       const unsigned short* __restrict__ wbuf,
                       float* __restrict__ out) {
    __shared__ __align__(16) unsigned short lds[25984];  // 51968 B -> 3 blk/CU
    unsigned short* XT  = lds;              // [64][266], dead after conv1
    unsigned short* Y1  = lds;              // [100][72] overlay
    unsigned short* W1s = lds + W1_OFF;     // [64][140]
    unsigned short* W2s = lds + W2_OFF;     // 2 x [64][72]
    unsigned short* Y2  = lds + Y2_OFF;     // [64][72]
    unsigned short* W3s = lds;              // [256][72] overlay (phase 3)

    const int tid = threadIdx.x;
    // ---- XCD-aware swizzle: (b,g) slab pinned to one XCD, pc fastest ----
    // bid%8 is the XCD round-robin heuristic; mapping errors only cost perf.
    int bid = blockIdx.x;                  // 3136 = 8 xcd * 8 slabs * 49 pat
    const int xcd  = bid & 7;
    int slot = bid >> 3;                   // 0..391
    const int bgl  = slot / 49;            // 0..7
    const int pat  = slot - bgl * 49;      // 0..48
    const int bg   = bgl * 8 + xcd;        // 0..63
    const int b    = bg >> 2;
    const int g    = bg & 3;
    const int pr   = pat / 7;
    const int pc   = pat - pr * 7;

    const float mval = mask[((b * 4 + g) * 7 + pr) * 7 + pc];
    const size_t xbase = (size_t)(b * 1024 + g * 256) * 3136
                       + (size_t)(pr * 8) * 56 + (size_t)(pc * 8);

    if (mval <= 0.f) {  // streaming passthrough: out = relu(x)
        for (int k = 0; k < 8; k++) {
            int v = tid + k * 256;
            int ch = v >> 3, py = v & 7;
            size_t off = xbase + (size_t)ch * 3136 + (size_t)py * 56;
            f4 d0 = *(const f4*)(x + off);
            f4 d1 = *(const f4*)(x + off + 4);
#pragma unroll
            for (int e = 0; e < 4; e++) {
                d0[e] = fmaxf(d0[e], 0.f);
                d1[e] = fmaxf(d1[e], 0.f);
            }
            __builtin_nontemporal_store(d0, (f4*)(out + off));
            __builtin_nontemporal_store(d1, (f4*)(out + off + 4));
        }
        return;
    }

    const int lane = tid & 63;
    const int wv   = tid >> 6;
    const int l15  = lane & 15;
    const int quad = lane >> 4;
    const int mrow = wv * 16 + l15;        // A-operand row (px)
    const int crow = wv * 16 + quad * 4;   // C/D row base (px)
    const int cpy  = crow >> 3, cpx0 = crow & 7;

    const unsigned short* W1g = wbuf + (size_t)g * 16384;
    const unsigned short* W2g = wbuf + 65536 + (size_t)g * 36864;
    const unsigned short* W3g = wbuf + 212992 + (size_t)g * 16384;

    // ---- stage X: fp32 [ch][8x8] -> bf16 XT[px][ic] ----
    for (int k = 0; k < 4; k++) {
        int v = tid + k * 256;
        int py = v & 7, chp = v >> 3;
        int ch = chp * 2;
        const float* s0 = x + xbase + (size_t)ch * 3136 + (size_t)py * 56;
        const float* s1 = s0 + 3136;
        f4 a0 = *(const f4*)s0, a1 = *(const f4*)(s0 + 4);
        f4 b0 = *(const f4*)s1, b1 = *(const f4*)(s1 + 4);
        float af[8] = {a0[0],a0[1],a0[2],a0[3],a1[0],a1[1],a1[2],a1[3]};
        float bg2[8] = {b0[0],b0[1],b0[2],b0[3],b1[0],b1[1],b1[2],b1[3]};
        int row0 = py * 8;
#pragma unroll
        for (int px = 0; px < 8; px++) {
            unsigned int u = (unsigned int)f2bf(af[px])
                           | ((unsigned int)f2bf(bg2[px]) << 16);
            *(unsigned int*)&XT[(row0 + px) * XT_S + ch] = u;
        }
    }
    // ---- stage W1 half 0 (coalesced 16B chunks); prefetch half 1 ----
    bfrag w1n[4];
#pragma unroll
    for (int j = 0; j < 4; j++) {
        int c = tid + 256 * j;             // chunk 0..1023
        int oc = c >> 4, ic0 = (c & 15) << 3;
        *(bfrag*)&W1s[oc * W1_S + ic0] = *(const bfrag*)&W1g[oc * 256 + ic0];
        w1n[j] = *(const bfrag*)&W1g[oc * 256 + 128 + ic0];
    }
    __syncthreads();  // B1

    // ---- conv1: C[64px x 64oc], K=256 in 2 halves ----
    f4 acc1[4];
#pragma unroll
    for (int nt = 0; nt < 4; nt++) acc1[nt] = (f4){0.f, 0.f, 0.f, 0.f};
#pragma unroll
    for (int ks = 0; ks < 4; ks++) {
        bfrag a = *(const bfrag*)&XT[mrow * XT_S + ks * 32 + quad * 8];
        __builtin_amdgcn_s_setprio(1);
#pragma unroll
        for (int nt = 0; nt < 4; nt++) {
            bfrag bb = *(const bfrag*)&W1s[(nt * 16 + l15) * W1_S + ks * 32 + quad * 8];
            acc1[nt] = __builtin_amdgcn_mfma_f32_16x16x32_bf16(a, bb, acc1[nt], 0, 0, 0);
        }
        __builtin_amdgcn_s_setprio(0);
    }
    __syncthreads();  // B2: half-0 weights dead
#pragma unroll
    for (int j = 0; j < 4; j++) {
        int c = tid + 256 * j;
        int oc = c >> 4, ic0 = (c & 15) << 3;
        *(bfrag*)&W1s[oc * W1_S + ic0] = w1n[j];
    }
    __syncthreads();  // B3: half-1 staged
#pragma unroll
    for (int ks = 0; ks < 4; ks++) {
        bfrag a = *(const bfrag*)&XT[mrow * XT_S + 128 + ks * 32 + quad * 8];
        __builtin_amdgcn_s_setprio(1);
#pragma unroll
        for (int nt = 0; nt < 4; nt++) {
            bfrag bb = *(const bfrag*)&W1s[(nt * 16 + l15) * W1_S + ks * 32 + quad * 8];
            acc1[nt] = __builtin_amdgcn_mfma_f32_16x16x32_bf16(a, bb, acc1[nt], 0, 0, 0);
        }
        __builtin_amdgcn_s_setprio(0);
    }
    __syncthreads();  // B4: XT + W1s dead

    // ---- Y1p: zero 36 border rows, write relu(acc1) interior ----
    for (int i = tid; i < 36 * 72; i += 256) {
        int j = i / 72, c = i - j * 72;
        int r = (j < 10) ? j : (j < 20 ? 80 + j
                                       : 10 + ((j - 20) >> 1) * 10 + ((j - 20) & 1) * 9);
        Y1[r * S72 + c] = 0;
    }
#pragma unroll
    for (int nt = 0; nt < 4; nt++)
#pragma unroll
        for (int r = 0; r < 4; r++) {
            int px = crow + r;
            int rowp = ((px >> 3) + 1) * 10 + (px & 7) + 1;
            float v = acc1[nt][r]; v = v > 0.f ? v : 0.f;
            Y1[rowp * S72 + nt * 16 + l15] = f2bf(v);
        }
    // stage W2 tap 0 into buf 0 (independent region)
#pragma unroll
    for (int j = 0; j < 2; j++) {
        int c = tid + 256 * j;             // chunk 0..511
        int oc = c >> 3, ic0 = (c & 7) << 3;
        *(bfrag*)&W2s[oc * S72 + ic0] = *(const bfrag*)&W2g[c * 8];
    }
    __syncthreads();  // B5

    // ---- conv2: 9 taps, W2 double-buffered, prefetch across barrier ----
    f4 acc2[4];
#pragma unroll
    for (int nt = 0; nt < 4; nt++) acc2[nt] = (f4){0.f, 0.f, 0.f, 0.f};
    const int apy = mrow >> 3, apx = mrow & 7;
    bfrag wst[2];

#define TAP(T) { \
    if ((T) < 8) { \
        _Pragma("unroll") \
        for (int j = 0; j < 2; j++) \
            wst[j] = *(const bfrag*)&W2g[((T) + 1) * 4096 + (tid + 256 * j) * 8]; \
    } \
    const int buf = ((T) & 1) * 4608; \
    const int rowp = (apy + (T) / 3) * 10 + apx + (T) % 3; \
    bfrag a0 = *(const bfrag*)&Y1[rowp * S72 + quad * 8]; \
    bfrag a1 = *(const bfrag*)&Y1[rowp * S72 + 32 + quad * 8]; \
    __builtin_amdgcn_s_setprio(1); \
    _Pragma("unroll") \
    for (int nt = 0; nt < 4; nt++) { \
        bfrag bb = *(const bfrag*)&W2s[buf + (nt * 16 + l15) * S72 + quad * 8]; \
        acc2[nt] = __builtin_amdgcn_mfma_f32_16x16x32_bf16(a0, bb, acc2[nt], 0, 0, 0); \
    } \
    _Pragma("unroll") \
    for (int nt = 0; nt < 4; nt++) { \
        bfrag bb = *(const bfrag*)&W2s[buf + (nt * 16 + l15) * S72 + 32 + quad * 8]; \
        acc2[nt] = __builtin_amdgcn_mfma_f32_16x16x32_bf16(a1, bb, acc2[nt], 0, 0, 0); \
    } \
    __builtin_amdgcn_s_setprio(0); \
    if ((T) < 8) { \
        const int nb = 4608 - buf; \
        _Pragma("unroll") \
        for (int j = 0; j < 2; j++) { \
            int c = tid + 256 * j; \
            *(bfrag*)&W2s[nb + (c >> 3) * S72 + ((c & 7) << 3)] = wst[j]; \
        } \
        __syncthreads(); \
    } }

    TAP(0) TAP(1) TAP(2) TAP(3) TAP(4) TAP(5) TAP(6) TAP(7) TAP(8)
#undef TAP

    // ---- Y2 = relu(acc2) (own region, write-then-barrier) ----
#pragma unroll
    for (int nt = 0; nt < 4; nt++)
#pragma unroll
        for (int r = 0; r < 4; r++) {
            int px = crow + r;
            float v = acc2[nt][r]; v = v > 0.f ? v : 0.f;
            Y2[px * S72 + nt * 16 + l15] = f2bf(v);
        }
    __syncthreads();  // B14: conv2 reads done, Y2 visible

    // ---- stage FULL W3 [256][72] over Y1+W2 regions ----
#pragma unroll
    for (int j = 0; j < 8; j++) {
        int c = tid + 256 * j;             // chunk 0..2047
        int oc = c >> 3, ic0 = (c & 7) << 3;
        *(bfrag*)&W3s[oc * S72 + ic0] = *(const bfrag*)&W3g[c * 8];
    }
    __syncthreads();  // B15

    // ---- conv3: 2 oc-halves; residual loads issued before MFMAs ----
#pragma unroll
    for (int hh = 0; hh < 2; hh++) {
        f4 rv[8];
#pragma unroll
        for (int nt = 0; nt < 8; nt++) {
            int oc = hh * 128 + nt * 16 + l15;
            rv[nt] = *(const f4*)(x + xbase + (size_t)oc * 3136
                                  + (size_t)cpy * 56 + cpx0);
        }
        f4 acc3[8];
#pragma unroll
        for (int nt = 0; nt < 8; nt++) acc3[nt] = (f4){0.f, 0.f, 0.f, 0.f};
#pragma unroll
        for (int ks = 0; ks < 2; ks++) {
            bfrag a = *(const bfrag*)&Y2[mrow * S72 + ks * 32 + quad * 8];
            __builtin_amdgcn_s_setprio(1);
#pragma unroll
            for (int nt = 0; nt < 8; nt++) {
                bfrag bb = *(const bfrag*)&W3s[(hh * 128 + nt * 16 + l15) * S72
                                               + ks * 32 + quad * 8];
                acc3[nt] = __builtin_amdgcn_mfma_f32_16x16x32_bf16(a, bb, acc3[nt], 0, 0, 0);
            }
            __builtin_amdgcn_s_setprio(0);
        }
#pragma unroll
        for (int nt = 0; nt < 8; nt++) {
            int oc = hh * 128 + nt * 16 + l15;
            f4 ov;
            ov[0] = fmaxf(acc3[nt][0] + rv[nt][0], 0.f);
            ov[1] = fmaxf(acc3[nt][1] + rv[nt][1], 0.f);
            ov[2] = fmaxf(acc3[nt][2] + rv[nt][2], 0.f);
            ov[3] = fmaxf(acc3[nt][3] + rv[nt][3], 0.f);
            __builtin_nontemporal_store(
                ov, (f4*)(out + xbase + (size_t)oc * 3136
                          + (size_t)cpy * 56 + cpx0));
        }
    }
}

extern "C" void kernel_launch(void* const* d_in, const int* in_sizes, int n_in,
                              void* d_out, int out_size, void* d_ws, size_t ws_size,
                              hipStream_t stream) {
    const float* x    = (const float*)d_in[0];
    const float* mask = (const float*)d_in[1];
    const float* w1   = (const float*)d_in[2];
    const float* w2   = (const float*)d_in[3];
    const float* w3   = (const float*)d_in[4];
    float* out = (float*)d_out;
    unsigned short* wbuf = (unsigned short*)d_ws;   // 557056 B

    prep_weights<<<dim3(1088), dim3(256), 0, stream>>>(w1, w2, w3, wbuf);
    bottleneck_kernel<<<dim3(16 * 7 * 7 * 4), dim3(256), 0, stream>>>(
        x, mask, wbuf, out);
}

// Round 5
// 480.244 us; speedup vs baseline: 1.4399x; 1.4399x over previous
//
#include <hip/hip_runtime.h>

// Bottleneck_refine: B=16, C=1024, H=W=56, G=4, MS=7 (8x8 patches), MID=256.
// One workgroup (256 thr = 4 waves) per (b,pr,pc,g): 3136 blocks.
//
// V5 = V3 + XCD-aware swizzle, PLAIN stores (V4b's nontemporal stores caused
// +42% WRITE_SIZE via partial-line HBM writes and halved effective BW).
//  - Swizzle: all 49 patches of one (b,g) slab -> SAME XCD (bid%8 heuristic),
//    pc fastest. The 7 pc-neighbors consuming each 128B x-line share one
//    XCD's L2 -> line fetched from HBM once (verified: FETCH 485->261 MB).
//  - LDS 51968 B -> 3 blocks/CU. Weights LDS-staged from bf16 prepped image.
//
// LDS overlay (shorts):
//   phase1: XT[64][266] @0 (17024) + W1s[64][140] @17024 (8960)  = 25984
//   phase2: Y1[100][72] @0 (7200) + W2dbuf 2x[64][72] @7200 (9216)
//           + Y2[64][72] @21376 (4608)
//   phase3: W3s[256][72] @0 (18432) + Y2 @21376
//
// d_ws (shorts): W1I[g][64][256] @0, W2I[g][9][64][64] @65536,
//                W3I[g][256][64] @212992.  total 557056 B.

typedef __attribute__((ext_vector_type(8))) short bfrag;      // 8 bf16
typedef __attribute__((ext_vector_type(4))) float f4;

__device__ __forceinline__ unsigned short f2bf(float f) {
    union { float f; unsigned int i; } v; v.f = f;
    unsigned int u = v.i;
    return (unsigned short)((u + 0x7FFFu + ((u >> 16) & 1u)) >> 16);
}

__global__ __launch_bounds__(256)
void prep_weights(const float* __restrict__ w1, const float* __restrict__ w2,
                  const float* __restrict__ w3, unsigned short* __restrict__ wb) {
    int i = blockIdx.x * 256 + threadIdx.x;   // 1088 blocks * 256 = 278528
    if (i < 65536) {
        wb[i] = f2bf(w1[i]);                  // [g*64+oc][ic]
    } else if (i < 212992) {
        int j = i - 65536;
        int ic = j & 63, ocl = (j >> 6) & 63, gt = j >> 12;  // gt = g*9+tap
        int tap = gt % 9, g = gt / 9;
        wb[i] = f2bf(w2[(size_t)((g * 64 + ocl) * 64 + ic) * 9 + tap]);
    } else {
        wb[i] = f2bf(w3[i - 212992]);         // [g*256+oc][ic]
    }
}

#define XT_S 266   // XT stride: 133 dw/row, odd -> conflict-light reads
#define W1_S 140   // 70 dw/row
#define S72  72    // Y1 / W2 / Y2 / W3 stride (36 dw/row)
#define W1_OFF 17024
#define W2_OFF 7200
#define Y2_OFF 21376

__global__ __launch_bounds__(256, 3)
void bottleneck_kernel(const float* __restrict__ x,
                       const float* __restrict__ mask,
                       const unsigned short* __restrict__ wbuf,
                       float* __restrict__ out) {
    __shared__ __align__(16) unsigned short lds[25984];  // 51968 B -> 3 blk/CU
    unsigned short* XT  = lds;              // [64][266], dead after conv1
    unsigned short* Y1  = lds;              // [100][72] overlay
    unsigned short* W1s = lds + W1_OFF;     // [64][140]
    unsigned short* W2s = lds + W2_OFF;     // 2 x [64][72]
    unsigned short* Y2  = lds + Y2_OFF;     // [64][72]
    unsigned short* W3s = lds;              // [256][72] overlay (phase 3)

    const int tid = threadIdx.x;
    // ---- XCD-aware swizzle: (b,g) slab pinned to one XCD, pc fastest ----
    int bid = blockIdx.x;                  // 3136 = 8 xcd * 8 slabs * 49 pat
    const int xcd  = bid & 7;
    int slot = bid >> 3;                   // 0..391
    const int bgl  = slot / 49;            // 0..7
    const int pat  = slot - bgl * 49;      // 0..48
    const int bg   = bgl * 8 + xcd;        // 0..63
    const int b    = bg >> 2;
    const int g    = bg & 3;
    const int pr   = pat / 7;
    const int pc   = pat - pr * 7;

    const float mval = mask[((b * 4 + g) * 7 + pr) * 7 + pc];
    const size_t xbase = (size_t)(b * 1024 + g * 256) * 3136
                       + (size_t)(pr * 8) * 56 + (size_t)(pc * 8);

    if (mval <= 0.f) {  // streaming passthrough: out = relu(x)
        for (int k = 0; k < 8; k++) {
            int v = tid + k * 256;
            int ch = v >> 3, py = v & 7;
            size_t off = xbase + (size_t)ch * 3136 + (size_t)py * 56;
            f4 d0 = *(const f4*)(x + off);
            f4 d1 = *(const f4*)(x + off + 4);
#pragma unroll
            for (int e = 0; e < 4; e++) {
                d0[e] = fmaxf(d0[e], 0.f);
                d1[e] = fmaxf(d1[e], 0.f);
            }
            *(f4*)(out + off)     = d0;
            *(f4*)(out + off + 4) = d1;
        }
        return;
    }

    const int lane = tid & 63;
    const int wv   = tid >> 6;
    const int l15  = lane & 15;
    const int quad = lane >> 4;
    const int mrow = wv * 16 + l15;        // A-operand row (px)
    const int crow = wv * 16 + quad * 4;   // C/D row base (px)
    const int cpy  = crow >> 3, cpx0 = crow & 7;

    const unsigned short* W1g = wbuf + (size_t)g * 16384;
    const unsigned short* W2g = wbuf + 65536 + (size_t)g * 36864;
    const unsigned short* W3g = wbuf + 212992 + (size_t)g * 16384;

    // ---- stage X: fp32 [ch][8x8] -> bf16 XT[px][ic] ----
    for (int k = 0; k < 4; k++) {
        int v = tid + k * 256;
        int py = v & 7, chp = v >> 3;
        int ch = chp * 2;
        const float* s0 = x + xbase + (size_t)ch * 3136 + (size_t)py * 56;
        const float* s1 = s0 + 3136;
        f4 a0 = *(const f4*)s0, a1 = *(const f4*)(s0 + 4);
        f4 b0 = *(const f4*)s1, b1 = *(const f4*)(s1 + 4);
        float af[8] = {a0[0],a0[1],a0[2],a0[3],a1[0],a1[1],a1[2],a1[3]};
        float bg2[8] = {b0[0],b0[1],b0[2],b0[3],b1[0],b1[1],b1[2],b1[3]};
        int row0 = py * 8;
#pragma unroll
        for (int px = 0; px < 8; px++) {
            unsigned int u = (unsigned int)f2bf(af[px])
                           | ((unsigned int)f2bf(bg2[px]) << 16);
            *(unsigned int*)&XT[(row0 + px) * XT_S + ch] = u;
        }
    }
    // ---- stage W1 half 0 (coalesced 16B chunks); prefetch half 1 ----
    bfrag w1n[4];
#pragma unroll
    for (int j = 0; j < 4; j++) {
        int c = tid + 256 * j;             // chunk 0..1023
        int oc = c >> 4, ic0 = (c & 15) << 3;
        *(bfrag*)&W1s[oc * W1_S + ic0] = *(const bfrag*)&W1g[oc * 256 + ic0];
        w1n[j] = *(const bfrag*)&W1g[oc * 256 + 128 + ic0];
    }
    __syncthreads();  // B1

    // ---- conv1: C[64px x 64oc], K=256 in 2 halves ----
    f4 acc1[4];
#pragma unroll
    for (int nt = 0; nt < 4; nt++) acc1[nt] = (f4){0.f, 0.f, 0.f, 0.f};
#pragma unroll
    for (int ks = 0; ks < 4; ks++) {
        bfrag a = *(const bfrag*)&XT[mrow * XT_S + ks * 32 + quad * 8];
        __builtin_amdgcn_s_setprio(1);
#pragma unroll
        for (int nt = 0; nt < 4; nt++) {
            bfrag bb = *(const bfrag*)&W1s[(nt * 16 + l15) * W1_S + ks * 32 + quad * 8];
            acc1[nt] = __builtin_amdgcn_mfma_f32_16x16x32_bf16(a, bb, acc1[nt], 0, 0, 0);
        }
        __builtin_amdgcn_s_setprio(0);
    }
    __syncthreads();  // B2: half-0 weights dead
#pragma unroll
    for (int j = 0; j < 4; j++) {
        int c = tid + 256 * j;
        int oc = c >> 4, ic0 = (c & 15) << 3;
        *(bfrag*)&W1s[oc * W1_S + ic0] = w1n[j];
    }
    __syncthreads();  // B3: half-1 staged
#pragma unroll
    for (int ks = 0; ks < 4; ks++) {
        bfrag a = *(const bfrag*)&XT[mrow * XT_S + 128 + ks * 32 + quad * 8];
        __builtin_amdgcn_s_setprio(1);
#pragma unroll
        for (int nt = 0; nt < 4; nt++) {
            bfrag bb = *(const bfrag*)&W1s[(nt * 16 + l15) * W1_S + ks * 32 + quad * 8];
            acc1[nt] = __builtin_amdgcn_mfma_f32_16x16x32_bf16(a, bb, acc1[nt], 0, 0, 0);
        }
        __builtin_amdgcn_s_setprio(0);
    }
    __syncthreads();  // B4: XT + W1s dead

    // ---- Y1p: zero 36 border rows, write relu(acc1) interior ----
    for (int i = tid; i < 36 * 72; i += 256) {
        int j = i / 72, c = i - j * 72;
        int r = (j < 10) ? j : (j < 20 ? 80 + j
                                       : 10 + ((j - 20) >> 1) * 10 + ((j - 20) & 1) * 9);
        Y1[r * S72 + c] = 0;
    }
#pragma unroll
    for (int nt = 0; nt < 4; nt++)
#pragma unroll
        for (int r = 0; r < 4; r++) {
            int px = crow + r;
            int rowp = ((px >> 3) + 1) * 10 + (px & 7) + 1;
            float v = acc1[nt][r]; v = v > 0.f ? v : 0.f;
            Y1[rowp * S72 + nt * 16 + l15] = f2bf(v);
        }
    // stage W2 tap 0 into buf 0 (independent region)
#pragma unroll
    for (int j = 0; j < 2; j++) {
        int c = tid + 256 * j;             // chunk 0..511
        int oc = c >> 3, ic0 = (c & 7) << 3;
        *(bfrag*)&W2s[oc * S72 + ic0] = *(const bfrag*)&W2g[c * 8];
    }
    __syncthreads();  // B5

    // ---- conv2: 9 taps, W2 double-buffered, prefetch across barrier ----
    f4 acc2[4];
#pragma unroll
    for (int nt = 0; nt < 4; nt++) acc2[nt] = (f4){0.f, 0.f, 0.f, 0.f};
    const int apy = mrow >> 3, apx = mrow & 7;
    bfrag wst[2];

#define TAP(T) { \
    if ((T) < 8) { \
        _Pragma("unroll") \
        for (int j = 0; j < 2; j++) \
            wst[j] = *(const bfrag*)&W2g[((T) + 1) * 4096 + (tid + 256 * j) * 8]; \
    } \
    const int buf = ((T) & 1) * 4608; \
    const int rowp = (apy + (T) / 3) * 10 + apx + (T) % 3; \
    bfrag a0 = *(const bfrag*)&Y1[rowp * S72 + quad * 8]; \
    bfrag a1 = *(const bfrag*)&Y1[rowp * S72 + 32 + quad * 8]; \
    __builtin_amdgcn_s_setprio(1); \
    _Pragma("unroll") \
    for (int nt = 0; nt < 4; nt++) { \
        bfrag bb = *(const bfrag*)&W2s[buf + (nt * 16 + l15) * S72 + quad * 8]; \
        acc2[nt] = __builtin_amdgcn_mfma_f32_16x16x32_bf16(a0, bb, acc2[nt], 0, 0, 0); \
    } \
    _Pragma("unroll") \
    for (int nt = 0; nt < 4; nt++) { \
        bfrag bb = *(const bfrag*)&W2s[buf + (nt * 16 + l15) * S72 + 32 + quad * 8]; \
        acc2[nt] = __builtin_amdgcn_mfma_f32_16x16x32_bf16(a1, bb, acc2[nt], 0, 0, 0); \
    } \
    __builtin_amdgcn_s_setprio(0); \
    if ((T) < 8) { \
        const int nb = 4608 - buf; \
        _Pragma("unroll") \
        for (int j = 0; j < 2; j++) { \
            int c = tid + 256 * j; \
            *(bfrag*)&W2s[nb + (c >> 3) * S72 + ((c & 7) << 3)] = wst[j]; \
        } \
        __syncthreads(); \
    } }

    TAP(0) TAP(1) TAP(2) TAP(3) TAP(4) TAP(5) TAP(6) TAP(7) TAP(8)
#undef TAP

    // ---- Y2 = relu(acc2) (own region, write-then-barrier) ----
#pragma unroll
    for (int nt = 0; nt < 4; nt++)
#pragma unroll
        for (int r = 0; r < 4; r++) {
            int px = crow + r;
            float v = acc2[nt][r]; v = v > 0.f ? v : 0.f;
            Y2[px * S72 + nt * 16 + l15] = f2bf(v);
        }
    __syncthreads();  // B14: conv2 reads done, Y2 visible

    // ---- stage FULL W3 [256][72] over Y1+W2 regions ----
#pragma unroll
    for (int j = 0; j < 8; j++) {
        int c = tid + 256 * j;             // chunk 0..2047
        int oc = c >> 3, ic0 = (c & 7) << 3;
        *(bfrag*)&W3s[oc * S72 + ic0] = *(const bfrag*)&W3g[c * 8];
    }
    __syncthreads();  // B15

    // ---- conv3: 2 oc-halves; residual loads issued before MFMAs ----
#pragma unroll
    for (int hh = 0; hh < 2; hh++) {
        f4 rv[8];
#pragma unroll
        for (int nt = 0; nt < 8; nt++) {
            int oc = hh * 128 + nt * 16 + l15;
            rv[nt] = *(const f4*)(x + xbase + (size_t)oc * 3136
                                  + (size_t)cpy * 56 + cpx0);
        }
        f4 acc3[8];
#pragma unroll
        for (int nt = 0; nt < 8; nt++) acc3[nt] = (f4){0.f, 0.f, 0.f, 0.f};
#pragma unroll
        for (int ks = 0; ks < 2; ks++) {
            bfrag a = *(const bfrag*)&Y2[mrow * S72 + ks * 32 + quad * 8];
            __builtin_amdgcn_s_setprio(1);
#pragma unroll
            for (int nt = 0; nt < 8; nt++) {
                bfrag bb = *(const bfrag*)&W3s[(hh * 128 + nt * 16 + l15) * S72
                                               + ks * 32 + quad * 8];
                acc3[nt] = __builtin_amdgcn_mfma_f32_16x16x32_bf16(a, bb, acc3[nt], 0, 0, 0);
            }
            __builtin_amdgcn_s_setprio(0);
        }
#pragma unroll
        for (int nt = 0; nt < 8; nt++) {
            int oc = hh * 128 + nt * 16 + l15;
            f4 ov;
            ov[0] = fmaxf(acc3[nt][0] + rv[nt][0], 0.f);
            ov[1] = fmaxf(acc3[nt][1] + rv[nt][1], 0.f);
            ov[2] = fmaxf(acc3[nt][2] + rv[nt][2], 0.f);
            ov[3] = fmaxf(acc3[nt][3] + rv[nt][3], 0.f);
            *(f4*)(out + xbase + (size_t)oc * 3136
                   + (size_t)cpy * 56 + cpx0) = ov;
        }
    }
}

extern "C" void kernel_launch(void* const* d_in, const int* in_sizes, int n_in,
                              void* d_out, int out_size, void* d_ws, size_t ws_size,
                              hipStream_t stream) {
    const float* x    = (const float*)d_in[0];
    const float* mask = (const float*)d_in[1];
    const float* w1   = (const float*)d_in[2];
    const float* w2   = (const float*)d_in[3];
    const float* w3   = (const float*)d_in[4];
    float* out = (float*)d_out;
    unsigned short* wbuf = (unsigned short*)d_ws;   // 557056 B

    prep_weights<<<dim3(1088), dim3(256), 0, stream>>>(w1, w2, w3, wbuf);
    bottleneck_kernel<<<dim3(16 * 7 * 7 * 4), dim3(256), 0, stream>>>(
        x, mask, wbuf, out);
}